// Round 16
// baseline (50.956 us; speedup 1.0000x reference)
//
#include <hip/hip_runtime.h>
#include <hip/hip_bf16.h>
#include <cstddef>

#define NAGENT 8
#define DIN    128
#define HID    64
#define NACT   16

typedef __attribute__((ext_vector_type(8))) short bf16x8;
typedef __attribute__((ext_vector_type(4))) float f32x4;

__device__ __forceinline__ short f2bf(float f) {
    __hip_bfloat16 h = __float2bfloat16(f);      // RNE; pairs pack to v_cvt_pk_bf16_f32
    union { __hip_bfloat16 h; short s; } u; u.h = h;
    return u.s;
}
__device__ __forceinline__ float sigmoid_f(float v) { return 1.0f / (1.0f + __expf(-v)); }
__device__ __forceinline__ float tanh_f(float v) {
    v = fminf(fmaxf(v, -15.0f), 15.0f);
    float e = __expf(2.0f * v);
    return (e - 1.0f) / (e + 1.0f);
}
__device__ __forceinline__ bf16x8 cvt8pair(float4 v0, float4 v1) {
    bf16x8 r;
    r[0] = f2bf(v0.x); r[1] = f2bf(v0.y); r[2] = f2bf(v0.z); r[3] = f2bf(v0.w);
    r[4] = f2bf(v1.x); r[5] = f2bf(v1.y); r[6] = f2bf(v1.z); r[7] = f2bf(v1.w);
    return r;
}

// ---------------- weight fp32 -> bf16 fragment-major packing ----------------
// Per-agent packed layout (shorts), base a*33792:
//   W1  chunks c in [0,1024):    c = (n*4+k)*64 + lane      -> W1[a][n*16+lr][k*32+lk*8 ..+8]
//   Wih chunks c in [1024,2560): c-1024 = ((g*4+n)*2+kk)*64+lane -> Wih[a][g*64+n*16+lr][kk*32+lk*8..]
//   Whh chunks c in [2560,4096): same with Whh
//   W2  chunks c in [4096,4224): c-4096 = kk*64+lane        -> W2[a][lr][kk*32+lk*8..]
extern "C" __global__ void __launch_bounds__(256)
conv_weights_packed(const float* __restrict__ W1, const float* __restrict__ Wih,
                    const float* __restrict__ Whh, const float* __restrict__ W2,
                    short* __restrict__ ws)
{
    const int a = blockIdx.y;
    const int c = blockIdx.x * 256 + threadIdx.x;
    if (c >= 4224) return;
    const int lane = c & 63, lr = lane & 15, lk = lane >> 4;
    const float* src;
    if (c < 1024) {
        int n = c >> 8, k = (c >> 6) & 3;
        src = W1 + a * 8192 + (n * 16 + lr) * 128 + k * 32 + lk * 8;
    } else if (c < 2560) {
        int idx = (c - 1024) >> 6;
        int g = idx >> 3, n = (idx >> 1) & 3, kk = idx & 1;
        src = Wih + a * 12288 + (g * 64 + n * 16 + lr) * 64 + kk * 32 + lk * 8;
    } else if (c < 4096) {
        int idx = (c - 2560) >> 6;
        int g = idx >> 3, n = (idx >> 1) & 3, kk = idx & 1;
        src = Whh + a * 12288 + (g * 64 + n * 16 + lr) * 64 + kk * 32 + lk * 8;
    } else {
        int kk = (c - 4096) >> 6;
        src = W2 + a * 1024 + lr * 64 + kk * 32 + lk * 8;
    }
    float4 v0 = ((const float4*)src)[0];
    float4 v1 = ((const float4*)src)[1];
    bf16x8 o = cvt8pair(v0, v1);
    *(bf16x8*)(ws + (size_t)a * 33792 + (size_t)c * 8) = o;
}

// ---------------- main fused kernel ----------------
// Champion r10/r13 body (48.5us, ~60 VGPR, zero spill, 32 waves/CU) with two
// zero-cost scheduling changes targeting the convoy effect (all 32 waves/CU
// in lockstep -> pipes idle in alternation; m114: MFMA/VALU co-execute only
// from waves at DIFFERENT phases):
//  (a) per-wave col-block rotation n = (ni + wid + bid>>3) & 3 — waves on a
//      SIMD touch different weight lines and stagger their elementwise phases;
//  (b) per kk-step: 6 weight loads issued textually before the 6 MFMAs (24
//      regs in flight, within budget) — one MFMA-overlapped vmcnt wait
//      instead of interleaved dependent stalls.
extern "C" __global__ void __launch_bounds__(256, 4)
rnn_main(const float* __restrict__ x,     // [B*A, D]
         const float* __restrict__ hin,   // [B, A, H]
         const float* __restrict__ b1, const float* __restrict__ bih,
         const float* __restrict__ bhh, const float* __restrict__ b2,
         const short* __restrict__ wsp,   // packed bf16 weights
         float* __restrict__ qout,        // [B*A, NACT]
         float* __restrict__ hout)        // [B, A, H]
{
    const int bid  = blockIdx.x;
    const int a    = bid & 7;             // one agent per CU (r13 layout)
    const int t    = threadIdx.x;
    const int wid  = t >> 6;              // 0..3
    const int lane = t & 63;
    const int lr   = lane & 15;
    const int lk   = lane >> 4;

    __shared__ short zs[4 * 1024];        // 4 per-wave 2KB transpose buffers
    char* zb = (char*)(zs + wid * 1024);

    const short* wsA = wsp + (size_t)a * 33792;
    const int tile = (bid >> 3) * 4 + wid;
    const int arow = tile * 16 + lr;

    // ---- x / h rows -> bf16 fragments ----
    const float* xrow = x + ((size_t)arow * NAGENT + a) * DIN + lk * 8;
    const float* hrow = hin + ((size_t)arow * NAGENT + a) * HID + lk * 8;
    bf16x8 hf0 = cvt8pair(*(const float4*)(hrow),      *(const float4*)(hrow + 4));
    bf16x8 hf1 = cvt8pair(*(const float4*)(hrow + 32), *(const float4*)(hrow + 36));

    // ---- fc1: z1 = relu(x @ W1^T + b1) ----
    {
        f32x4 acc1[4];
        #pragma unroll
        for (int n = 0; n < 4; ++n) {
            float bv = b1[a * HID + n * 16 + lr];
            acc1[n] = (f32x4){bv, bv, bv, bv};
        }
        #pragma unroll
        for (int k = 0; k < 4; ++k) {
            bf16x8 xk = cvt8pair(*(const float4*)(xrow + k * 32),
                                 *(const float4*)(xrow + k * 32 + 4));
            #pragma unroll
            for (int n = 0; n < 4; ++n) {
                bf16x8 wb = *(const bf16x8*)(wsA + ((n * 4 + k) * 64 + lane) * 8);
                acc1[n] = __builtin_amdgcn_mfma_f32_16x16x32_bf16(xk, wb, acc1[n], 0, 0, 0);
            }
        }
        #pragma unroll
        for (int n = 0; n < 4; ++n)
            #pragma unroll
            for (int j = 0; j < 4; ++j) {
                int row = lk * 4 + j, col = n * 16 + lr;
                *(short*)(zb + row * 128 + ((col * 2) ^ ((row & 7) << 4))) =
                    f2bf(fmaxf(acc1[n][j], 0.0f));
            }
    }

    // ---- z1 back as A-fragments ----
    bf16x8 za0 = *(const bf16x8*)(zb + lr * 128 + ((0 * 64 + lk * 16) ^ ((lr & 7) << 4)));
    bf16x8 za1 = *(const bf16x8*)(zb + lr * 128 + ((1 * 64 + lk * 16) ^ ((lr & 7) << 4)));

    // ---- GRU gates, column-block-wise, ROTATED start per wave/block ----
    #pragma unroll 1
    for (int ni = 0; ni < 4; ++ni) {
        const int n = (ni + wid + (bid >> 3)) & 3;

        float bhr = bhh[a * 192 +   0 + n * 16 + lr];
        float bhz = bhh[a * 192 +  64 + n * 16 + lr];
        float bhn = bhh[a * 192 + 128 + n * 16 + lr];
        float bir = bih[a * 192 +   0 + n * 16 + lr];
        float biz = bih[a * 192 +  64 + n * 16 + lr];
        float bin_ = bih[a * 192 + 128 + n * 16 + lr];
        f32x4 aHr = (f32x4){bhr, bhr, bhr, bhr};
        f32x4 aHz = (f32x4){bhz, bhz, bhz, bhz};
        f32x4 aHn = (f32x4){bhn, bhn, bhn, bhn};
        f32x4 aIr = (f32x4){bir, bir, bir, bir};
        f32x4 aIz = (f32x4){biz, biz, biz, biz};
        f32x4 aIn = (f32x4){bin_, bin_, bin_, bin_};

        #pragma unroll
        for (int kk = 0; kk < 2; ++kk) {
            bf16x8 hfk = kk ? hf1 : hf0;
            bf16x8 zak = kk ? za1 : za0;
            // all 6 weight loads first (one vmcnt window) ...
            bf16x8 whr = *(const bf16x8*)(wsA + 20480 + (((0 * 4 + n) * 2 + kk) * 64 + lane) * 8);
            bf16x8 whz = *(const bf16x8*)(wsA + 20480 + (((1 * 4 + n) * 2 + kk) * 64 + lane) * 8);
            bf16x8 whn = *(const bf16x8*)(wsA + 20480 + (((2 * 4 + n) * 2 + kk) * 64 + lane) * 8);
            bf16x8 wir = *(const bf16x8*)(wsA + 8192 + (((0 * 4 + n) * 2 + kk) * 64 + lane) * 8);
            bf16x8 wiz = *(const bf16x8*)(wsA + 8192 + (((1 * 4 + n) * 2 + kk) * 64 + lane) * 8);
            bf16x8 win = *(const bf16x8*)(wsA + 8192 + (((2 * 4 + n) * 2 + kk) * 64 + lane) * 8);
            // ... then the 6 MFMAs
            aHr = __builtin_amdgcn_mfma_f32_16x16x32_bf16(hfk, whr, aHr, 0, 0, 0);
            aHz = __builtin_amdgcn_mfma_f32_16x16x32_bf16(hfk, whz, aHz, 0, 0, 0);
            aHn = __builtin_amdgcn_mfma_f32_16x16x32_bf16(hfk, whn, aHn, 0, 0, 0);
            aIr = __builtin_amdgcn_mfma_f32_16x16x32_bf16(zak, wir, aIr, 0, 0, 0);
            aIz = __builtin_amdgcn_mfma_f32_16x16x32_bf16(zak, wiz, aIz, 0, 0, 0);
            aIn = __builtin_amdgcn_mfma_f32_16x16x32_bf16(zak, win, aIn, 0, 0, 0);
        }

        // elementwise + stores for this col-block
        #pragma unroll
        for (int j = 0; j < 4; ++j) {
            int row = lk * 4 + j, col = n * 16 + lr;
            float hp = hin[((size_t)(tile * 16 + row) * NAGENT + a) * HID + col];
            float r  = sigmoid_f(aIr[j] + aHr[j]);
            float zv = sigmoid_f(aIz[j] + aHz[j]);
            float nn = tanh_f(aIn[j] + r * aHn[j]);
            float hv = (1.0f - zv) * nn + zv * hp;
            hout[((size_t)(tile * 16 + row) * NAGENT + a) * HID + col] = hv;
            *(short*)(zb + row * 128 + ((col * 2) ^ ((row & 7) << 4))) = f2bf(hv);
        }
    }

    // ---- fc2: q = h_new @ W2^T + b2 ----
    {
        float bq = b2[a * NACT + lr];
        f32x4 q = (f32x4){bq, bq, bq, bq};
        bf16x8 ha0 = *(const bf16x8*)(zb + lr * 128 + ((0 * 64 + lk * 16) ^ ((lr & 7) << 4)));
        bf16x8 ha1 = *(const bf16x8*)(zb + lr * 128 + ((1 * 64 + lk * 16) ^ ((lr & 7) << 4)));
        bf16x8 w2f0 = *(const bf16x8*)(wsA + 32768 + (0 * 64 + lane) * 8);
        bf16x8 w2f1 = *(const bf16x8*)(wsA + 32768 + (1 * 64 + lane) * 8);
        q = __builtin_amdgcn_mfma_f32_16x16x32_bf16(ha0, w2f0, q, 0, 0, 0);
        q = __builtin_amdgcn_mfma_f32_16x16x32_bf16(ha1, w2f1, q, 0, 0, 0);
        #pragma unroll
        for (int j = 0; j < 4; ++j)
            qout[((size_t)(tile * 16 + lk * 4 + j) * NAGENT + a) * NACT + lr] = q[j];
    }
}

extern "C" void kernel_launch(void* const* d_in, const int* in_sizes, int n_in,
                              void* d_out, int out_size, void* d_ws, size_t ws_size,
                              hipStream_t stream)
{
    const float* x   = (const float*)d_in[0];
    const float* hin = (const float*)d_in[1];
    const float* W1  = (const float*)d_in[2];
    const float* b1  = (const float*)d_in[3];
    const float* Wih = (const float*)d_in[4];
    const float* bih = (const float*)d_in[5];
    const float* Whh = (const float*)d_in[6];
    const float* bhh = (const float*)d_in[7];
    const float* W2  = (const float*)d_in[8];
    const float* b2  = (const float*)d_in[9];

    const int B = in_sizes[0] / (NAGENT * DIN);   // 16384

    float* qout = (float*)d_out;                              // [B*A, NACT]
    float* hout = (float*)d_out + (size_t)B * NAGENT * NACT;  // [B, A, H]

    short* wsp = (short*)d_ws;                                // 540,672 B packed

    conv_weights_packed<<<dim3(17, NAGENT), 256, 0, stream>>>(W1, Wih, Whh, W2, wsp);

    // 1-D grid: 2048 blocks; agent = bid & 7 (one agent per CU under linear
    // round-robin dispatch since 256 % 8 == 0).
    dim3 grid((B / 64) * NAGENT);
    rnn_main<<<grid, 256, 0, stream>>>(x, hin, b1, bih, bhh, b2, wsp, qout, hout);
}

// Round 17
// 47.949 us; speedup vs baseline: 1.0627x; 1.0627x over previous
//
#include <hip/hip_runtime.h>
#include <hip/hip_bf16.h>
#include <cstddef>

#define NAGENT 8
#define DIN    128
#define HID    64
#define NACT   16

typedef __attribute__((ext_vector_type(8))) short bf16x8;
typedef __attribute__((ext_vector_type(4))) float f32x4;

__device__ __forceinline__ short f2bf(float f) {
    __hip_bfloat16 h = __float2bfloat16(f);      // RNE; pairs pack to v_cvt_pk_bf16_f32
    union { __hip_bfloat16 h; short s; } u; u.h = h;
    return u.s;
}
__device__ __forceinline__ float sigmoid_f(float v) { return 1.0f / (1.0f + __expf(-v)); }
__device__ __forceinline__ float tanh_f(float v) {
    v = fminf(fmaxf(v, -15.0f), 15.0f);
    float e = __expf(2.0f * v);
    return (e - 1.0f) / (e + 1.0f);
}
__device__ __forceinline__ bf16x8 cvt8pair(float4 v0, float4 v1) {
    bf16x8 r;
    r[0] = f2bf(v0.x); r[1] = f2bf(v0.y); r[2] = f2bf(v0.z); r[3] = f2bf(v0.w);
    r[4] = f2bf(v1.x); r[5] = f2bf(v1.y); r[6] = f2bf(v1.z); r[7] = f2bf(v1.w);
    return r;
}
__device__ __forceinline__ void gload_lds16(const void* g, void* l) {
    __builtin_amdgcn_global_load_lds(
        (const __attribute__((address_space(1))) unsigned int*)g,
        (__attribute__((address_space(3))) unsigned int*)l, 16, 0, 0);
}

// ---------------- weight fp32 -> bf16 fragment-major packing ----------------
// Per-agent packed layout (shorts), base a*33792; 1KB rounds (512 shorts):
//   W1  rounds  0..15 : f=(n*4+k)        -> W1[a][n*16+lr][k*32+lk*8]
//   Wih rounds 16..39 : 16+(g*4+n)*2+kk  -> Wih[a][g*64+n*16+lr][kk*32+lk*8]
//   Whh rounds 40..63 : 40+(g*4+n)*2+kk  -> Whh[...]
//   W2  rounds 64..65 : 64+kk            -> W2[a][lr][kk*32+lk*8]
extern "C" __global__ void __launch_bounds__(256)
conv_weights_packed(const float* __restrict__ W1, const float* __restrict__ Wih,
                    const float* __restrict__ Whh, const float* __restrict__ W2,
                    short* __restrict__ ws)
{
    const int a = blockIdx.y;
    const int c = blockIdx.x * 256 + threadIdx.x;
    if (c >= 4224) return;
    const int lane = c & 63, lr = lane & 15, lk = lane >> 4;
    const float* src;
    if (c < 1024) {
        int n = c >> 8, k = (c >> 6) & 3;
        src = W1 + a * 8192 + (n * 16 + lr) * 128 + k * 32 + lk * 8;
    } else if (c < 2560) {
        int idx = (c - 1024) >> 6;
        int g = idx >> 3, n = (idx >> 1) & 3, kk = idx & 1;
        src = Wih + a * 12288 + (g * 64 + n * 16 + lr) * 64 + kk * 32 + lk * 8;
    } else if (c < 4096) {
        int idx = (c - 2560) >> 6;
        int g = idx >> 3, n = (idx >> 1) & 3, kk = idx & 1;
        src = Whh + a * 12288 + (g * 64 + n * 16 + lr) * 64 + kk * 32 + lk * 8;
    } else {
        int kk = (c - 4096) >> 6;
        src = W2 + a * 1024 + lr * 64 + kk * 32 + lk * 8;
    }
    float4 v0 = ((const float4*)src)[0];
    float4 v1 = ((const float4*)src)[1];
    bf16x8 o = cvt8pair(v0, v1);
    *(bf16x8*)(ws + (size_t)a * 33792 + (size_t)c * 8) = o;
}

// ---------------- main fused kernel ----------------
// Champion structure (48.5us: 2048 blocks, 4 waves, 1 tile/wave, 64-VGPR
// tier, agent-per-CU) + T3-CORRECT double-buffered block-shared weight
// staging: STAGE(next phase -> other buffer) issued BEFORE compute(current),
// ONE barrier per phase (r15's stage->barrier->compute drain-0 was the
// known-broken pattern). 11 phases: fc1 x3, then {i-path, h-path} x 4
// col-blocks. Weight reads become ds_read_b128 with immediate offsets
// (kills most of the 64-bit global addressing VALU). Biases folded into
// elementwise (acc init 0) so no load gates accumulator init; hp issued
// one phase early. LDS = 2x6KB wbuf + 4x2KB zs = 20480B -> 8 blocks/CU.
extern "C" __global__ void __launch_bounds__(256, 4)
rnn_main(const float* __restrict__ x,     // [B*A, D]
         const float* __restrict__ hin,   // [B, A, H]
         const float* __restrict__ b1, const float* __restrict__ bih,
         const float* __restrict__ bhh, const float* __restrict__ b2,
         const short* __restrict__ wsp,   // packed bf16 weights
         float* __restrict__ qout,        // [B*A, NACT]
         float* __restrict__ hout)        // [B, A, H]
{
    const int bid  = blockIdx.x;
    const int a    = bid & 7;             // one agent per CU
    const int t    = threadIdx.x;
    const int wid  = t >> 6;              // 0..3
    const int lane = t & 63;
    const int lr   = lane & 15;
    const int lk   = lane >> 4;

    __shared__ short wbuf[2 * 3072];      // 12 KB double-buffered weight stage
    __shared__ short zs[4 * 1024];        // 8 KB per-wave transpose buffers
    char* zb = (char*)(zs + wid * 1024);
    const char* wb0 = (const char*)wbuf;          // buf0 bytes
    const char* wb1 = (const char*)(wbuf + 3072); // buf1 bytes

    const short* wsA = wsp + (size_t)a * 33792;
    const int tile = (bid >> 3) * 4 + wid;
    const int arow = tile * 16 + lr;

    // stage one 6-round phase: slots {wid, wid+4(if wid<2)}; round = rbase(slot)
    #define STAGE6(dstbuf, REXPR)                                                   \
        { int s = wid;  int rr = (REXPR);                                           \
          gload_lds16(wsA + (size_t)rr * 512 + lane * 8, (dstbuf) + s * 512);       \
          if (wid < 2) { s = wid + 4; rr = (REXPR);                                 \
            gload_lds16(wsA + (size_t)rr * 512 + lane * 8, (dstbuf) + s * 512); } }

    // ---- prologue: stage p0 (fc1 rounds 0..5) into buf0 ----
    STAGE6(wbuf, s)

    const float* xrow = x + ((size_t)arow * NAGENT + a) * DIN + lk * 8;
    const float* hrow = hin + ((size_t)arow * NAGENT + a) * HID + lk * 8;
    bf16x8 xf[4];
    #pragma unroll
    for (int k = 0; k < 4; ++k)
        xf[k] = cvt8pair(*(const float4*)(xrow + k * 32),
                         *(const float4*)(xrow + k * 32 + 4));
    bf16x8 hf0 = cvt8pair(*(const float4*)(hrow),      *(const float4*)(hrow + 4));
    bf16x8 hf1 = cvt8pair(*(const float4*)(hrow + 32), *(const float4*)(hrow + 36));
    float b1v[4];
    #pragma unroll
    for (int n = 0; n < 4; ++n) b1v[n] = b1[a * HID + n * 16 + lr];

    f32x4 acc1[4];
    #pragma unroll
    for (int n = 0; n < 4; ++n) acc1[n] = (f32x4){0.f, 0.f, 0.f, 0.f};

    __syncthreads();                      // buf0[p0] ready

    // ---- p0: stage p1 -> buf1; compute fc1 frags 0..5 from buf0 ----
    STAGE6(wbuf + 3072, 6 + s)
    #pragma unroll
    for (int s = 0; s < 6; ++s) {
        bf16x8 w = *(const bf16x8*)(wb0 + s * 1024 + lane * 16);
        acc1[s >> 2] = __builtin_amdgcn_mfma_f32_16x16x32_bf16(xf[s & 3], w, acc1[s >> 2], 0, 0, 0);
    }
    __syncthreads();

    // ---- p1: stage p2 (rounds 12..15) -> buf0; compute frags 6..11 from buf1 ----
    gload_lds16(wsA + (size_t)(12 + wid) * 512 + lane * 8, wbuf + wid * 512);
    #pragma unroll
    for (int s = 0; s < 6; ++s) {
        int f = 6 + s;
        bf16x8 w = *(const bf16x8*)(wb1 + s * 1024 + lane * 16);
        acc1[f >> 2] = __builtin_amdgcn_mfma_f32_16x16x32_bf16(xf[f & 3], w, acc1[f >> 2], 0, 0, 0);
    }
    __syncthreads();

    // ---- p2: stage i-path(n=0) -> buf1; compute frags 12..15 from buf0; z1 -> zs ----
    STAGE6(wbuf + 3072, 16 + 0 * 2 + (s >> 1) * 8 + (s & 1))
    #pragma unroll
    for (int s = 0; s < 4; ++s) {
        bf16x8 w = *(const bf16x8*)(wb0 + s * 1024 + lane * 16);
        acc1[3] = __builtin_amdgcn_mfma_f32_16x16x32_bf16(xf[s], w, acc1[3], 0, 0, 0);
    }
    #pragma unroll
    for (int n = 0; n < 4; ++n)
        #pragma unroll
        for (int j = 0; j < 4; ++j) {
            int row = lk * 4 + j, col = n * 16 + lr;
            *(short*)(zb + row * 128 + ((col * 2) ^ ((row & 7) << 4))) =
                f2bf(fmaxf(acc1[n][j] + b1v[n], 0.0f));
        }
    __syncthreads();                      // buf1[i0] ready

    bf16x8 za0 = *(const bf16x8*)(zb + lr * 128 + ((0 * 64 + lk * 16) ^ ((lr & 7) << 4)));
    bf16x8 za1 = *(const bf16x8*)(zb + lr * 128 + ((1 * 64 + lk * 16) ^ ((lr & 7) << 4)));

    // ---- gates: per col-block n: {i-phase reads buf1, stages h(n)->buf0;
    //                               h-phase reads buf0, stages i(n+1)->buf1} ----
    #pragma unroll 1
    for (int n = 0; n < 4; ++n) {
        // i-phase
        STAGE6(wbuf, 40 + n * 2 + (s >> 1) * 8 + (s & 1))
        float hp[4];
        #pragma unroll
        for (int j = 0; j < 4; ++j)
            hp[j] = hin[((size_t)(tile * 16 + lk * 4 + j) * NAGENT + a) * HID + n * 16 + lr];
        float bsr  = bih[a * 192 +   0 + n * 16 + lr] + bhh[a * 192 +   0 + n * 16 + lr];
        float bsz  = bih[a * 192 +  64 + n * 16 + lr] + bhh[a * 192 +  64 + n * 16 + lr];
        float bin_ = bih[a * 192 + 128 + n * 16 + lr];
        float bhn_ = bhh[a * 192 + 128 + n * 16 + lr];

        f32x4 aI0 = (f32x4){0.f,0.f,0.f,0.f}, aI1 = aI0, aI2 = aI0;
        {
            bf16x8 w0 = *(const bf16x8*)(wb1 + 0 * 1024 + lane * 16);
            bf16x8 w1 = *(const bf16x8*)(wb1 + 1 * 1024 + lane * 16);
            bf16x8 w2 = *(const bf16x8*)(wb1 + 2 * 1024 + lane * 16);
            bf16x8 w3 = *(const bf16x8*)(wb1 + 3 * 1024 + lane * 16);
            bf16x8 w4 = *(const bf16x8*)(wb1 + 4 * 1024 + lane * 16);
            bf16x8 w5 = *(const bf16x8*)(wb1 + 5 * 1024 + lane * 16);
            aI0 = __builtin_amdgcn_mfma_f32_16x16x32_bf16(za0, w0, aI0, 0, 0, 0);
            aI0 = __builtin_amdgcn_mfma_f32_16x16x32_bf16(za1, w1, aI0, 0, 0, 0);
            aI1 = __builtin_amdgcn_mfma_f32_16x16x32_bf16(za0, w2, aI1, 0, 0, 0);
            aI1 = __builtin_amdgcn_mfma_f32_16x16x32_bf16(za1, w3, aI1, 0, 0, 0);
            aI2 = __builtin_amdgcn_mfma_f32_16x16x32_bf16(za0, w4, aI2, 0, 0, 0);
            aI2 = __builtin_amdgcn_mfma_f32_16x16x32_bf16(za1, w5, aI2, 0, 0, 0);
        }
        __syncthreads();                  // buf0[h(n)] ready

        // h-phase
        if (n < 3) {
            STAGE6(wbuf + 3072, 16 + (n + 1) * 2 + (s >> 1) * 8 + (s & 1))
        }
        f32x4 aH0 = (f32x4){0.f,0.f,0.f,0.f}, aH1 = aH0, aH2 = aH0;
        {
            bf16x8 w0 = *(const bf16x8*)(wb0 + 0 * 1024 + lane * 16);
            bf16x8 w1 = *(const bf16x8*)(wb0 + 1 * 1024 + lane * 16);
            bf16x8 w2 = *(const bf16x8*)(wb0 + 2 * 1024 + lane * 16);
            bf16x8 w3 = *(const bf16x8*)(wb0 + 3 * 1024 + lane * 16);
            bf16x8 w4 = *(const bf16x8*)(wb0 + 4 * 1024 + lane * 16);
            bf16x8 w5 = *(const bf16x8*)(wb0 + 5 * 1024 + lane * 16);
            aH0 = __builtin_amdgcn_mfma_f32_16x16x32_bf16(hf0, w0, aH0, 0, 0, 0);
            aH0 = __builtin_amdgcn_mfma_f32_16x16x32_bf16(hf1, w1, aH0, 0, 0, 0);
            aH1 = __builtin_amdgcn_mfma_f32_16x16x32_bf16(hf0, w2, aH1, 0, 0, 0);
            aH1 = __builtin_amdgcn_mfma_f32_16x16x32_bf16(hf1, w3, aH1, 0, 0, 0);
            aH2 = __builtin_amdgcn_mfma_f32_16x16x32_bf16(hf0, w4, aH2, 0, 0, 0);
            aH2 = __builtin_amdgcn_mfma_f32_16x16x32_bf16(hf1, w5, aH2, 0, 0, 0);
        }
        #pragma unroll
        for (int j = 0; j < 4; ++j) {
            int row = lk * 4 + j, col = n * 16 + lr;
            float r  = sigmoid_f(aI0[j] + aH0[j] + bsr);
            float zv = sigmoid_f(aI1[j] + aH1[j] + bsz);
            float nn = tanh_f((aI2[j] + bin_) + r * (aH2[j] + bhn_));
            float hv = (1.0f - zv) * nn + zv * hp[j];
            hout[((size_t)(tile * 16 + row) * NAGENT + a) * HID + col] = hv;
            *(short*)(zb + row * 128 + ((col * 2) ^ ((row & 7) << 4))) = f2bf(hv);
        }
        if (n < 3) __syncthreads();       // buf1[i(n+1)] ready
    }

    // ---- fc2: q = h_new @ W2^T + b2 (W2 from L2; zs is per-wave) ----
    {
        float bq = b2[a * NACT + lr];
        f32x4 q = (f32x4){bq, bq, bq, bq};
        bf16x8 ha0 = *(const bf16x8*)(zb + lr * 128 + ((0 * 64 + lk * 16) ^ ((lr & 7) << 4)));
        bf16x8 ha1 = *(const bf16x8*)(zb + lr * 128 + ((1 * 64 + lk * 16) ^ ((lr & 7) << 4)));
        bf16x8 w2f0 = *(const bf16x8*)(wsA + 32768 + (0 * 64 + lane) * 8);
        bf16x8 w2f1 = *(const bf16x8*)(wsA + 32768 + (1 * 64 + lane) * 8);
        q = __builtin_amdgcn_mfma_f32_16x16x32_bf16(ha0, w2f0, q, 0, 0, 0);
        q = __builtin_amdgcn_mfma_f32_16x16x32_bf16(ha1, w2f1, q, 0, 0, 0);
        #pragma unroll
        for (int j = 0; j < 4; ++j)
            qout[((size_t)(tile * 16 + lk * 4 + j) * NAGENT + a) * NACT + lr] = q[j];
    }
    #undef STAGE6
}

extern "C" void kernel_launch(void* const* d_in, const int* in_sizes, int n_in,
                              void* d_out, int out_size, void* d_ws, size_t ws_size,
                              hipStream_t stream)
{
    const float* x   = (const float*)d_in[0];
    const float* hin = (const float*)d_in[1];
    const float* W1  = (const float*)d_in[2];
    const float* b1  = (const float*)d_in[3];
    const float* Wih = (const float*)d_in[4];
    const float* bih = (const float*)d_in[5];
    const float* Whh = (const float*)d_in[6];
    const float* bhh = (const float*)d_in[7];
    const float* W2  = (const float*)d_in[8];
    const float* b2  = (const float*)d_in[9];

    const int B = in_sizes[0] / (NAGENT * DIN);   // 16384

    float* qout = (float*)d_out;                              // [B*A, NACT]
    float* hout = (float*)d_out + (size_t)B * NAGENT * NACT;  // [B, A, H]

    short* wsp = (short*)d_ws;                                // 540,672 B packed

    conv_weights_packed<<<dim3(17, NAGENT), 256, 0, stream>>>(W1, Wih, Whh, W2, wsp);

    // 1-D grid: 2048 blocks; agent = bid & 7 (one agent per CU under linear
    // round-robin dispatch since 256 % 8 == 0).
    dim3 grid((B / 64) * NAGENT);
    rnn_main<<<grid, 256, 0, stream>>>(x, hin, b1, bih, bhh, b2, wsp, qout, hout);
}